// Round 1
// baseline (849.661 us; speedup 1.0000x reference)
//
#include <hip/hip_runtime.h>

typedef unsigned long long u64;

#define TOK 16384
#define KK 8192
#define DD 256

#define BM 128
#define BN 128
#define DK 32

// ---------------- init: zero ws accumulators ----------------
__global__ void vq_init_kernel(float* __restrict__ sums, u64* __restrict__ best,
                               int* __restrict__ counts, float* __restrict__ nsum) {
    int gid = blockIdx.x * 256 + threadIdx.x;        // 2048 blocks -> 524288 threads
#pragma unroll
    for (int i = 0; i < 4; i++) {
        sums[gid + i * 524288] = 0.0f;               // 2097152 floats
    }
    if (gid < TOK) best[gid] = 0xFFFFFFFFFFFFFFFFULL;
    if (gid < KK)  counts[gid] = 0;
    if (gid == 0)  *nsum = 0.0f;
}

// ---------------- e2[k] = sum_d emb[d][k]^2 ----------------
__global__ void vq_e2_kernel(const float* __restrict__ emb, float* __restrict__ e2) {
    int k = blockIdx.x * 256 + threadIdx.x;          // 32 blocks
    float s = 0.0f;
    for (int d = 0; d < DD; d++) {
        float v = emb[(size_t)d * KK + k];           // coalesced across k
        s = fmaf(v, v, s);
    }
    e2[k] = s;
}

// ---------------- x2[t] = sum_d x[t][d]^2 (wave per token) ----------------
__global__ void vq_x2_kernel(const float* __restrict__ x, float* __restrict__ x2) {
    int t = blockIdx.x * 4 + (threadIdx.x >> 6);     // 4096 blocks, 4 waves/block
    int lane = threadIdx.x & 63;
    float4 v = *(const float4*)(x + (size_t)t * DD + lane * 4);
    float p = v.x * v.x + v.y * v.y + v.z * v.z + v.w * v.w;
#pragma unroll
    for (int off = 32; off > 0; off >>= 1) p += __shfl_down(p, off, 64);
    if (lane == 0) x2[t] = p;
}

// ---------------- embT[k][d] = emb[d][k] ----------------
__global__ void vq_transpose_kernel(const float* __restrict__ emb, float* __restrict__ embT) {
    __shared__ float tile[32][33];
    int tx = threadIdx.x & 31, ty = threadIdx.x >> 5;    // 32x8 threads
    int k0 = blockIdx.x * 32, d0 = blockIdx.y * 32;      // grid (256, 8)
#pragma unroll
    for (int j = 0; j < 4; j++) {
        int d = ty * 4 + j;
        tile[d][tx] = emb[(size_t)(d0 + d) * KK + k0 + tx];
    }
    __syncthreads();
#pragma unroll
    for (int j = 0; j < 4; j++) {
        int k = ty * 4 + j;
        embT[(size_t)(k0 + k) * DD + d0 + tx] = tile[tx][k];
    }
}

// ---------------- fused distance + argmin ----------------
// dist[t][k] = (x2[t] + e2[k]) - 2*dot(x[t], emb[:,k]), fp32, reference rounding order.
// Per-token argmin via packed (dist_bits<<32 | k) u64 atomicMin -> lowest index wins ties.
__global__ __launch_bounds__(256) void vq_argmin_kernel(
        const float* __restrict__ x, const float* __restrict__ emb,
        const float* __restrict__ x2, const float* __restrict__ e2,
        u64* __restrict__ best) {
    __shared__ float xs[DK][BM + 4];   // transposed x tile: xs[d][t]
    __shared__ float es[DK][BN + 4];   // emb tile: es[d][k]
    __shared__ u64 red[BM][17];

    const int tid = threadIdx.x;
    const int tx = tid & 15, ty = tid >> 4;
    const int k0 = blockIdx.x * BN;
    const int t0 = blockIdx.y * BM;

    float acc[8][8];
#pragma unroll
    for (int i = 0; i < 8; i++)
#pragma unroll
        for (int j = 0; j < 8; j++) acc[i][j] = 0.0f;

    for (int dc = 0; dc < DD; dc += DK) {
        __syncthreads();
        // stage emb tile [DK][BN] (direct, coalesced)
#pragma unroll
        for (int i = 0; i < 4; i++) {
            int s = tid + i * 256;
            int r = s >> 5, c = (s & 31) << 2;
            float4 v = *(const float4*)(emb + (size_t)(dc + r) * KK + k0 + c);
            *(float4*)&es[r][c] = v;
        }
        // stage x tile transposed [DK][BM]
#pragma unroll
        for (int i = 0; i < 4; i++) {
            int s = tid + i * 256;
            int row = s >> 3, c = (s & 7) << 2;
            float4 v = *(const float4*)(x + (size_t)(t0 + row) * DD + dc + c);
            xs[c + 0][row] = v.x;
            xs[c + 1][row] = v.y;
            xs[c + 2][row] = v.z;
            xs[c + 3][row] = v.w;
        }
        __syncthreads();
#pragma unroll 4
        for (int d = 0; d < DK; d++) {
            float4 a0 = *(const float4*)&xs[d][ty * 4];
            float4 a1 = *(const float4*)&xs[d][64 + ty * 4];
            float4 b0 = *(const float4*)&es[d][tx * 4];
            float4 b1 = *(const float4*)&es[d][64 + tx * 4];
            float a[8] = {a0.x, a0.y, a0.z, a0.w, a1.x, a1.y, a1.z, a1.w};
            float b[8] = {b0.x, b0.y, b0.z, b0.w, b1.x, b1.y, b1.z, b1.w};
#pragma unroll
            for (int i = 0; i < 8; i++)
#pragma unroll
                for (int j = 0; j < 8; j++)
                    acc[i][j] = fmaf(a[i], b[j], acc[i][j]);
        }
    }

    // epilogue: distances + per-thread argmin over its 8 codes, per token row
#pragma unroll
    for (int i = 0; i < 8; i++) {
        int row = (i < 4) ? (ty * 4 + i) : (64 + ty * 4 + (i - 4));
        float sx2 = x2[t0 + row];
        u64 bestp = 0xFFFFFFFFFFFFFFFFULL;
#pragma unroll
        for (int j = 0; j < 8; j++) {
            int col = (j < 4) ? (tx * 4 + j) : (64 + tx * 4 + (j - 4));
            int kg = k0 + col;
            float s = sx2 + e2[kg];           // rounded add (matches ref)
            float td = 2.0f * acc[i][j];      // exact (power-of-2 scale)
            asm volatile("" : "+v"(td));      // block fma contraction into the subtract
            float dist = s - td;              // rounded sub (matches ref)
            u64 p = ((u64)__float_as_uint(dist) << 32) | (unsigned)kg;
            bestp = p < bestp ? p : bestp;
        }
        red[row][tx] = bestp;
    }
    __syncthreads();
    if (tid < BM) {
        u64 mn = red[tid][0];
#pragma unroll
        for (int j = 1; j < 16; j++) {
            u64 v = red[tid][j];
            mn = v < mn ? v : mn;
        }
        atomicMin(&best[t0 + tid], mn);
    }
}

// ---------------- extract indices + counts ----------------
__global__ void vq_indices_kernel(const u64* __restrict__ best, int* __restrict__ indices,
                                  int* __restrict__ counts) {
    int t = blockIdx.x * 256 + threadIdx.x;          // 64 blocks
    int idx = (int)(best[t] & 0xFFFFFFFFULL);
    indices[t] = idx;
    atomicAdd(&counts[idx], 1);
}

// ---------------- new_N + N_sum ----------------
__global__ void vq_newN_kernel(const float* __restrict__ N, const int* __restrict__ counts,
                               float* __restrict__ outN, float* __restrict__ nsum) {
    int k = blockIdx.x * 256 + threadIdx.x;          // 32 blocks
    float a = 0.99f * N[k];
    float b = 0.01f * (float)counts[k];
    float nN = a + b;
    outN[k] = nN;
    float s = nN;
#pragma unroll
    for (int off = 32; off > 0; off >>= 1) s += __shfl_down(s, off, 64);
    __shared__ float wsum[4];
    int lane = threadIdx.x & 63, w = threadIdx.x >> 6;
    if (lane == 0) wsum[w] = s;
    __syncthreads();
    if (threadIdx.x == 0) atomicAdd(nsum, wsum[0] + wsum[1] + wsum[2] + wsum[3]);
}

// ---------------- quantized_st = x + (q - x) ----------------
__global__ void vq_gather_kernel(const float* __restrict__ x, const float* __restrict__ embT,
                                 const int* __restrict__ indices, float* __restrict__ out0) {
    int gid = blockIdx.x * 256 + threadIdx.x;        // 4096 blocks, 1M threads
    int t = gid >> 6, c = (gid & 63) << 2;
    float4 xv = *(const float4*)(x + (size_t)t * DD + c);
    float4 qv = *(const float4*)(embT + (size_t)indices[t] * DD + c);
    float4 o;
    o.x = xv.x + (qv.x - xv.x);
    o.y = xv.y + (qv.y - xv.y);
    o.z = xv.z + (qv.z - xv.z);
    o.w = xv.w + (qv.w - xv.w);
    *(float4*)(out0 + (size_t)t * DD + c) = o;
}

// ---------------- sums[k][d] += x[t][d] for idx[t]==k ----------------
__global__ void vq_scatter_kernel(const float* __restrict__ x, const int* __restrict__ indices,
                                  float* __restrict__ sums) {
    int t = blockIdx.x * 4 + (threadIdx.x >> 6);     // 4096 blocks, wave per token
    int lane = threadIdx.x & 63;
    int idx = indices[t];
    float4 xv = *(const float4*)(x + (size_t)t * DD + lane * 4);
    float* base = sums + (size_t)idx * DD + lane * 4;
    atomicAdd(base + 0, xv.x);
    atomicAdd(base + 1, xv.y);
    atomicAdd(base + 2, xv.z);
    atomicAdd(base + 3, xv.w);
}

// ---------------- new_m and new_embeddings ----------------
__global__ void vq_final_kernel(const float* __restrict__ m, const float* __restrict__ sums,
                                const float* __restrict__ outN, const float* __restrict__ nsum,
                                float* __restrict__ outEmb, float* __restrict__ outM) {
    int gid = blockIdx.x * 256 + threadIdx.x;        // 8192 blocks, 2M threads
    int k = gid & (KK - 1);
    int d = gid >> 13;
    float Nsum = *nsum;
    float nN = outN[k];
    float scaled = (nN + 1e-5f) / (Nsum + 0.08192f) * Nsum;   // K*EPS = 0.08192
    float a = 0.99f * m[gid];
    float b = 0.01f * sums[(size_t)k * DD + d];
    float mv = a + b;
    outM[gid] = mv;
    outEmb[gid] = mv / scaled;
}

extern "C" void kernel_launch(void* const* d_in, const int* in_sizes, int n_in,
                              void* d_out, int out_size, void* d_ws, size_t ws_size,
                              hipStream_t stream) {
    const float* x   = (const float*)d_in[0];   // [16,32,32,256] -> [16384][256]
    const float* emb = (const float*)d_in[1];   // [256][8192]
    const float* Nin = (const float*)d_in[2];   // [8192]
    const float* min = (const float*)d_in[3];   // [256][8192]

    float* out0   = (float*)d_out;              // quantized_st  [16384*256]
    float* outEmb = out0 + 4194304;             // new_embeddings [256*8192]
    float* outN   = outEmb + 2097152;           // new_N [8192]
    float* outM   = outN + 8192;                // new_m [256*8192]

    // workspace layout (floats)
    float* ws      = (float*)d_ws;
    float* sums    = ws;                        // 2097152 (8 MB)  [K][D]
    float* e2buf   = ws + 2097152;              // 8192
    float* x2buf   = e2buf + 8192;              // 16384
    u64*   best    = (u64*)(x2buf + 16384);     // 16384 u64 (32768 f)
    int*   idxbuf  = (int*)(best + 16384);      // 16384
    int*   counts  = idxbuf + 16384;            // 8192
    float* nsum    = (float*)(counts + 8192);   // 1
    // embT staged in the new_m output region (overwritten by vq_final_kernel last)
    float* embT    = outM;                      // 2097152  [K][D]

    vq_init_kernel<<<2048, 256, 0, stream>>>(sums, best, counts, nsum);
    vq_e2_kernel<<<32, 256, 0, stream>>>(emb, e2buf);
    vq_x2_kernel<<<4096, 256, 0, stream>>>(x, x2buf);
    vq_transpose_kernel<<<dim3(256, 8), 256, 0, stream>>>(emb, embT);
    vq_argmin_kernel<<<dim3(KK / BN, TOK / BM), 256, 0, stream>>>(x, emb, x2buf, e2buf, best);
    vq_indices_kernel<<<64, 256, 0, stream>>>(best, idxbuf, counts);
    vq_newN_kernel<<<32, 256, 0, stream>>>(Nin, counts, outN, nsum);
    vq_gather_kernel<<<4096, 256, 0, stream>>>(x, embT, idxbuf, out0);
    vq_scatter_kernel<<<4096, 256, 0, stream>>>(x, idxbuf, sums);
    vq_final_kernel<<<8192, 256, 0, stream>>>(min, sums, outN, nsum, outEmb, outM);
}

// Round 2
// 332.417 us; speedup vs baseline: 2.5560x; 2.5560x over previous
//
#include <hip/hip_runtime.h>

typedef unsigned long long u64;
typedef _Float16 f16;
typedef f16 f16x8 __attribute__((ext_vector_type(8)));
typedef f16 f16x4 __attribute__((ext_vector_type(4)));
typedef float f32x4 __attribute__((ext_vector_type(4)));

#define TOK 16384
#define KK 8192
#define DD 256

#define BM 128
#define BN 128
#define BK 32

#define SCALE 4096.0f                 // 2^12, exact
#define DESCALE (1.0f/8388608.0f)     // 2^-23 = 2^-24 (limb scale^2) * 2 (ref's 2*dot)

// ---------------- init: zero ws accumulators ----------------
__global__ void vq_init_kernel(float* __restrict__ sums, u64* __restrict__ best,
                               int* __restrict__ counts, float* __restrict__ nsum) {
    int gid = blockIdx.x * 256 + threadIdx.x;        // 2048 blocks
#pragma unroll
    for (int i = 0; i < 4; i++) {
        sums[gid + i * 524288] = 0.0f;
    }
    if (gid < TOK) best[gid] = 0xFFFFFFFFFFFFFFFFULL;
    if (gid < KK)  counts[gid] = 0;
    if (gid == 0)  *nsum = 0.0f;
}

// ---------------- e2[k] = sum_d emb[d][k]^2 ----------------
__global__ void vq_e2_kernel(const float* __restrict__ emb, float* __restrict__ e2) {
    int k = blockIdx.x * 256 + threadIdx.x;
    float s = 0.0f;
    for (int d = 0; d < DD; d++) {
        float v = emb[(size_t)d * KK + k];
        s = fmaf(v, v, s);
    }
    e2[k] = s;
}

// ---------------- x2[t] = sum_d x[t][d]^2 ----------------
__global__ void vq_x2_kernel(const float* __restrict__ x, float* __restrict__ x2) {
    int t = blockIdx.x * 4 + (threadIdx.x >> 6);
    int lane = threadIdx.x & 63;
    float4 v = *(const float4*)(x + (size_t)t * DD + lane * 4);
    float p = v.x * v.x + v.y * v.y + v.z * v.z + v.w * v.w;
#pragma unroll
    for (int off = 32; off > 0; off >>= 1) p += __shfl_down(p, off, 64);
    if (lane == 0) x2[t] = p;
}

// ---------------- split x into scaled fp16 limbs ----------------
__global__ void vq_splitx_kernel(const float* __restrict__ x, f16* __restrict__ xh,
                                 f16* __restrict__ xl) {
    int gid = blockIdx.x * 256 + threadIdx.x;        // 4096 blocks, 4 elems/thread
    float4 v = *(const float4*)(x + (size_t)gid * 4);
    f16x4 h, l;
    float s;
    s = v.x * SCALE; h.x = (f16)s; l.x = (f16)(s - (float)h.x);
    s = v.y * SCALE; h.y = (f16)s; l.y = (f16)(s - (float)h.y);
    s = v.z * SCALE; h.z = (f16)s; l.z = (f16)(s - (float)h.z);
    s = v.w * SCALE; h.w = (f16)s; l.w = (f16)(s - (float)h.w);
    *(f16x4*)(xh + (size_t)gid * 4) = h;
    *(f16x4*)(xl + (size_t)gid * 4) = l;
}

// ---------------- transpose emb -> embT (fp32) + scaled fp16 limbs ----------------
__global__ void vq_trsplit_kernel(const float* __restrict__ emb, float* __restrict__ embT,
                                  f16* __restrict__ eh, f16* __restrict__ el) {
    __shared__ float tile[32][33];
    int tx = threadIdx.x & 31, ty = threadIdx.x >> 5;    // 32x8 threads
    int k0 = blockIdx.x * 32, d0 = blockIdx.y * 32;      // grid (256, 8)
#pragma unroll
    for (int j = 0; j < 4; j++) {
        int d = ty * 4 + j;
        tile[d][tx] = emb[(size_t)(d0 + d) * KK + k0 + tx];
    }
    __syncthreads();
#pragma unroll
    for (int j = 0; j < 4; j++) {
        int k = ty * 4 + j;
        float v = tile[tx][k];
        size_t o = (size_t)(k0 + k) * DD + d0 + tx;
        embT[o] = v;
        float sv = v * SCALE;
        f16 h = (f16)sv;
        eh[o] = h;
        el[o] = (f16)(sv - (float)h);
    }
}

// ---------------- fused distance + argmin via fp16-split MFMA ----------------
// dot = xh*eh + xh*el + xl*eh (limb products exact in fp32 acc; err ~2^-22 rel)
// dist = (x2[t] + e2[k]) - acc*2^-23, fp32 rounding sequence matching the ref.
__global__ __launch_bounds__(256, 2) void vq_argmin_kernel(
        const f16* __restrict__ xh, const f16* __restrict__ xl,
        const f16* __restrict__ eh, const f16* __restrict__ el,
        const float* __restrict__ x2, const float* __restrict__ e2,
        u64* __restrict__ best) {
    __shared__ char lds[32768];    // 4 tiles of [128][32] f16: xh, xl, eh, el
    __shared__ u64 red[BM];

    const int tid = threadIdx.x;
    const int lane = tid & 63;
    const int w = tid >> 6;                 // wave 0..3, 2x2 over 128x128
    const int k0 = blockIdx.x * BN;
    const int t0 = blockIdx.y * BM;
    const int wrow = (w >> 1) * 64;
    const int wcol = (w & 1) * 64;
    const int lrow = lane & 15;
    const int kg = lane >> 4;

    // wave w stages tile w (8 KB each)
    const char* gsrc;
    if (w == 0)      gsrc = (const char*)(xh + (size_t)t0 * DD);
    else if (w == 1) gsrc = (const char*)(xl + (size_t)t0 * DD);
    else if (w == 2) gsrc = (const char*)(eh + (size_t)k0 * DD);
    else             gsrc = (const char*)(el + (size_t)k0 * DD);
    char* lbase = lds + w * 8192;

    f32x4 acc[4][4];
#pragma unroll
    for (int mi = 0; mi < 4; mi++)
#pragma unroll
        for (int ni = 0; ni < 4; ni++) {
            f32x4 z = {0.0f, 0.0f, 0.0f, 0.0f};
            acc[mi][ni] = z;
        }

    for (int dc = 0; dc < DD; dc += BK) {
        __syncthreads();
        // stage: linear LDS dest, XOR-swizzle applied on the GLOBAL source
        // (kg_data = slot ^ ((row>>1)&3)) so swizzled ds_read below is its inverse.
#pragma unroll
        for (int is = 0; is < 8; is++) {
            int p = is * 1024 + lane * 16;
            int row = p >> 6;
            int slot = (p >> 4) & 3;
            int kgd = slot ^ ((row >> 1) & 3);
            const char* g = gsrc + (size_t)row * (DD * 2) + dc * 2 + kgd * 16;
            __builtin_amdgcn_global_load_lds(
                (const __attribute__((address_space(1))) unsigned int*)g,
                (__attribute__((address_space(3))) unsigned int*)(lbase + p), 16, 0, 0);
        }
        __syncthreads();

        f16x8 axh[4], axl[4], beh[4], bel[4];
#pragma unroll
        for (int mi = 0; mi < 4; mi++) {
            int row = wrow + mi * 16 + lrow;
            int off = row * 64 + ((kg ^ ((row >> 1) & 3)) << 4);
            axh[mi] = *(const f16x8*)(lds + off);
            axl[mi] = *(const f16x8*)(lds + 8192 + off);
        }
#pragma unroll
        for (int ni = 0; ni < 4; ni++) {
            int row = wcol + ni * 16 + lrow;
            int off = row * 64 + ((kg ^ ((row >> 1) & 3)) << 4);
            beh[ni] = *(const f16x8*)(lds + 16384 + off);
            bel[ni] = *(const f16x8*)(lds + 24576 + off);
        }
#pragma unroll
        for (int mi = 0; mi < 4; mi++)
#pragma unroll
            for (int ni = 0; ni < 4; ni++) {
                acc[mi][ni] = __builtin_amdgcn_mfma_f32_16x16x32_f16(axh[mi], beh[ni], acc[mi][ni], 0, 0, 0);
                acc[mi][ni] = __builtin_amdgcn_mfma_f32_16x16x32_f16(axh[mi], bel[ni], acc[mi][ni], 0, 0, 0);
                acc[mi][ni] = __builtin_amdgcn_mfma_f32_16x16x32_f16(axl[mi], beh[ni], acc[mi][ni], 0, 0, 0);
            }
    }

    // epilogue: C/D layout col=lane&15, row=(lane>>4)*4+reg (m89-verified, dtype-indep)
    __syncthreads();
    if (tid < BM) red[tid] = 0xFFFFFFFFFFFFFFFFULL;
    __syncthreads();
#pragma unroll
    for (int mi = 0; mi < 4; mi++) {
#pragma unroll
        for (int r = 0; r < 4; r++) {
            int rowl = wrow + mi * 16 + kg * 4 + r;
            float sx2 = x2[t0 + rowl];
            u64 b = 0xFFFFFFFFFFFFFFFFULL;
#pragma unroll
            for (int ni = 0; ni < 4; ni++) {
                int coll = wcol + ni * 16 + lrow;
                int kgl = k0 + coll;
                float s = sx2 + e2[kgl];          // rounded add (matches ref)
                float td = acc[mi][ni][r] * DESCALE;   // exact pow2 scale
                asm volatile("" : "+v"(td));
                float dist = s - td;              // rounded sub (matches ref)
                u64 p = ((u64)__float_as_uint(dist) << 32) | (unsigned)kgl;
                b = p < b ? p : b;
            }
            // min across the 16 lanes holding the same rows (different cols)
#pragma unroll
            for (int off2 = 1; off2 < 16; off2 <<= 1) {
                u64 o = __shfl_xor(b, off2, 64);
                b = o < b ? o : b;
            }
            if (lrow == 0) atomicMin(&red[rowl], b);
        }
    }
    __syncthreads();
    if (tid < BM) atomicMin(&best[t0 + tid], red[tid]);
}

// ---------------- extract indices + counts ----------------
__global__ void vq_indices_kernel(const u64* __restrict__ best, int* __restrict__ indices,
                                  int* __restrict__ counts) {
    int t = blockIdx.x * 256 + threadIdx.x;
    int idx = (int)(best[t] & 0xFFFFFFFFULL);
    indices[t] = idx;
    atomicAdd(&counts[idx], 1);
}

// ---------------- new_N + N_sum ----------------
__global__ void vq_newN_kernel(const float* __restrict__ N, const int* __restrict__ counts,
                               float* __restrict__ outN, float* __restrict__ nsum) {
    int k = blockIdx.x * 256 + threadIdx.x;
    float a = 0.99f * N[k];
    float b = 0.01f * (float)counts[k];
    float nN = a + b;
    outN[k] = nN;
    float s = nN;
#pragma unroll
    for (int off = 32; off > 0; off >>= 1) s += __shfl_down(s, off, 64);
    __shared__ float wsum[4];
    int lane = threadIdx.x & 63, w = threadIdx.x >> 6;
    if (lane == 0) wsum[w] = s;
    __syncthreads();
    if (threadIdx.x == 0) atomicAdd(nsum, wsum[0] + wsum[1] + wsum[2] + wsum[3]);
}

// ---------------- quantized_st = x + (q - x) ----------------
__global__ void vq_gather_kernel(const float* __restrict__ x, const float* __restrict__ embT,
                                 const int* __restrict__ indices, float* __restrict__ out0) {
    int gid = blockIdx.x * 256 + threadIdx.x;
    int t = gid >> 6, c = (gid & 63) << 2;
    float4 xv = *(const float4*)(x + (size_t)t * DD + c);
    float4 qv = *(const float4*)(embT + (size_t)indices[t] * DD + c);
    float4 o;
    o.x = xv.x + (qv.x - xv.x);
    o.y = xv.y + (qv.y - xv.y);
    o.z = xv.z + (qv.z - xv.z);
    o.w = xv.w + (qv.w - xv.w);
    *(float4*)(out0 + (size_t)t * DD + c) = o;
}

// ---------------- sums[k][d] += x[t][d] ----------------
__global__ void vq_scatter_kernel(const float* __restrict__ x, const int* __restrict__ indices,
                                  float* __restrict__ sums) {
    int t = blockIdx.x * 4 + (threadIdx.x >> 6);
    int lane = threadIdx.x & 63;
    int idx = indices[t];
    float4 xv = *(const float4*)(x + (size_t)t * DD + lane * 4);
    float* base = sums + (size_t)idx * DD + lane * 4;
    atomicAdd(base + 0, xv.x);
    atomicAdd(base + 1, xv.y);
    atomicAdd(base + 2, xv.z);
    atomicAdd(base + 3, xv.w);
}

// ---------------- new_m and new_embeddings ----------------
__global__ void vq_final_kernel(const float* __restrict__ m, const float* __restrict__ sums,
                                const float* __restrict__ outN, const float* __restrict__ nsum,
                                float* __restrict__ outEmb, float* __restrict__ outM) {
    int gid = blockIdx.x * 256 + threadIdx.x;
    int k = gid & (KK - 1);
    int d = gid >> 13;
    float Nsum = *nsum;
    float nN = outN[k];
    float scaled = (nN + 1e-5f) / (Nsum + 0.08192f) * Nsum;
    float a = 0.99f * m[gid];
    float b = 0.01f * sums[(size_t)k * DD + d];
    float mv = a + b;
    outM[gid] = mv;
    outEmb[gid] = mv / scaled;
}

extern "C" void kernel_launch(void* const* d_in, const int* in_sizes, int n_in,
                              void* d_out, int out_size, void* d_ws, size_t ws_size,
                              hipStream_t stream) {
    const float* x   = (const float*)d_in[0];   // [16384][256]
    const float* emb = (const float*)d_in[1];   // [256][8192]
    const float* Nin = (const float*)d_in[2];   // [8192]
    const float* min = (const float*)d_in[3];   // [256][8192]

    float* out0   = (float*)d_out;              // quantized_st  [4194304]
    float* outEmb = out0 + 4194304;             // new_embeddings [2097152]
    float* outN   = outEmb + 2097152;           // new_N [8192]
    float* outM   = outN + 8192;                // new_m [2097152]

    // workspace (floats)
    float* ws      = (float*)d_ws;
    float* sums    = ws;                        // 2097152
    float* e2buf   = ws + 2097152;              // 8192
    float* x2buf   = e2buf + 8192;              // 16384
    u64*   best    = (u64*)(x2buf + 16384);     // 16384 u64
    int*   idxbuf  = (int*)(best + 16384);      // 16384
    int*   counts  = idxbuf + 16384;            // 8192
    float* nsum    = (float*)(counts + 8192);   // 1

    // fp16 limbs + fp32 embT staged in output regions that are written later:
    f16* xhb = (f16*)out0;                      // 4194304 f16 = 8 MB
    f16* xlb = xhb + 4194304;                   // 8 MB (out0 is 16 MB total)
    f16* ehb = (f16*)outEmb;                    // 2097152 f16 = 4 MB
    f16* elb = ehb + 2097152;                   // 4 MB (outEmb is 8 MB)
    float* embT = outM;                         // 8 MB, overwritten by vq_final last

    vq_init_kernel<<<2048, 256, 0, stream>>>(sums, best, counts, nsum);
    vq_e2_kernel<<<32, 256, 0, stream>>>(emb, e2buf);
    vq_x2_kernel<<<4096, 256, 0, stream>>>(x, x2buf);
    vq_splitx_kernel<<<4096, 256, 0, stream>>>(x, xhb, xlb);
    vq_trsplit_kernel<<<dim3(256, 8), 256, 0, stream>>>(emb, embT, ehb, elb);
    vq_argmin_kernel<<<dim3(KK / BN, TOK / BM), 256, 0, stream>>>(
        xhb, xlb, ehb, elb, x2buf, e2buf, best);
    vq_indices_kernel<<<64, 256, 0, stream>>>(best, idxbuf, counts);
    vq_newN_kernel<<<32, 256, 0, stream>>>(Nin, counts, outN, nsum);
    vq_gather_kernel<<<4096, 256, 0, stream>>>(x, embT, idxbuf, out0);
    vq_scatter_kernel<<<4096, 256, 0, stream>>>(x, idxbuf, sums);
    vq_final_kernel<<<8192, 256, 0, stream>>>(min, sums, outN, nsum, outEmb, outM);
}

// Round 3
// 324.101 us; speedup vs baseline: 2.6216x; 1.0257x over previous
//
#include <hip/hip_runtime.h>

typedef unsigned long long u64;
typedef _Float16 f16;
typedef f16 f16x8 __attribute__((ext_vector_type(8)));
typedef f16 f16x4 __attribute__((ext_vector_type(4)));
typedef float f32x4 __attribute__((ext_vector_type(4)));

#define TOK 16384
#define KK 8192
#define DD 256

#define BM 256
#define BN 256
#define BK 32
#define NT 8          // DD/BK K-steps

#define SCALE 4096.0f                 // 2^12, exact
#define DESCALE (1.0f/8388608.0f)     // 2^-23 = 2^-24 (limb^2) * 2 (ref's 2*dot)

// ---------------- init: zero ws accumulators ----------------
__global__ void vq_init_kernel(float* __restrict__ sums, u64* __restrict__ best,
                               int* __restrict__ counts, float* __restrict__ nsum) {
    int gid = blockIdx.x * 256 + threadIdx.x;        // 2048 blocks
#pragma unroll
    for (int i = 0; i < 4; i++) {
        sums[gid + i * 524288] = 0.0f;
    }
    if (gid < TOK) best[gid] = 0xFFFFFFFFFFFFFFFFULL;
    if (gid < KK)  counts[gid] = 0;
    if (gid == 0)  *nsum = 0.0f;
}

// ---------------- e2[k] = sum_d emb[d][k]^2 (bit-identical to round 2) ----------------
__global__ void vq_e2_kernel(const float* __restrict__ emb, float* __restrict__ e2) {
    int k = blockIdx.x * 256 + threadIdx.x;
    float s = 0.0f;
    for (int d = 0; d < DD; d++) {
        float v = emb[(size_t)d * KK + k];
        s = fmaf(v, v, s);
    }
    e2[k] = s;
}

// ---------------- fused: x2[t] + fp16 limb split of x ----------------
__global__ void vq_x2split_kernel(const float* __restrict__ x, float* __restrict__ x2,
                                  f16* __restrict__ xh, f16* __restrict__ xl) {
    int t = blockIdx.x * 4 + (threadIdx.x >> 6);     // 4096 blocks, wave per token
    int lane = threadIdx.x & 63;
    size_t o = (size_t)t * DD + lane * 4;
    float4 v = *(const float4*)(x + o);
    f16x4 h, l;
    float s;
    s = v.x * SCALE; h.x = (f16)s; l.x = (f16)(s - (float)h.x);
    s = v.y * SCALE; h.y = (f16)s; l.y = (f16)(s - (float)h.y);
    s = v.z * SCALE; h.z = (f16)s; l.z = (f16)(s - (float)h.z);
    s = v.w * SCALE; h.w = (f16)s; l.w = (f16)(s - (float)h.w);
    *(f16x4*)(xh + o) = h;
    *(f16x4*)(xl + o) = l;
    float p = v.x * v.x + v.y * v.y + v.z * v.z + v.w * v.w;   // same expr as round 2
#pragma unroll
    for (int off = 32; off > 0; off >>= 1) p += __shfl_down(p, off, 64);
    if (lane == 0) x2[t] = p;
}

// ---------------- transpose emb -> embT (fp32) + scaled fp16 limbs ----------------
__global__ void vq_trsplit_kernel(const float* __restrict__ emb, float* __restrict__ embT,
                                  f16* __restrict__ eh, f16* __restrict__ el) {
    __shared__ float tile[32][33];
    int tx = threadIdx.x & 31, ty = threadIdx.x >> 5;    // 32x8 threads
    int k0 = blockIdx.x * 32, d0 = blockIdx.y * 32;      // grid (256, 8)
#pragma unroll
    for (int j = 0; j < 4; j++) {
        int d = ty * 4 + j;
        tile[d][tx] = emb[(size_t)(d0 + d) * KK + k0 + tx];
    }
    __syncthreads();
#pragma unroll
    for (int j = 0; j < 4; j++) {
        int k = ty * 4 + j;
        float v = tile[tx][k];
        size_t o = (size_t)(k0 + k) * DD + d0 + tx;
        embT[o] = v;
        float sv = v * SCALE;
        f16 h = (f16)sv;
        eh[o] = h;
        el[o] = (f16)(sv - (float)h);
    }
}

// ---------------- fused distance + argmin: 256x256 tile, min-2-phase pipeline ----
// LDS (dynamic 128KB): 2 bufs x { xh[256][32], xl, eh, el } f16, 16KB each.
// Stage for K-step t+1 issued at top of iteration t; single vmcnt(0)+barrier at
// the boundary (via __syncthreads) -> loads overlap ~all of the 96 MFMAs.
// Accumulation order per cell per K-chunk: hh, hl, lh (bit-identical to round 2).
__global__ __launch_bounds__(512, 2) void vq_argmin_kernel(
        const f16* __restrict__ xh, const f16* __restrict__ xl,
        const f16* __restrict__ eh, const f16* __restrict__ el,
        const float* __restrict__ x2, const float* __restrict__ e2,
        u64* __restrict__ best) {
    extern __shared__ char lds[];          // 131072 bytes

    const int tid = threadIdx.x;
    const int lane = tid & 63;
    const int wid = tid >> 6;              // 8 waves: 2 (rows) x 4 (cols)
    const int wr = wid >> 2;               // 0..1 -> row offset wr*128
    const int wc = wid & 3;                // 0..3 -> col offset wc*64
    const int lrow = lane & 15;
    const int kg = lane >> 4;
    const int kgx = ((kg ^ ((lrow >> 1) & 3)) << 4);   // swizzled 16B slot for ds_read
    const int k0 = blockIdx.x * BN;
    const int t0 = blockIdx.y * BM;

    // staging: 8 issues/thread/K-step; issue is covers subtile st=is>>1,
    // rows (is&1)*128 + tid/4. Pre-swizzled GLOBAL source, linear LDS dest.
    const char* gaddr[8];
    int laddr[8];
    {
        const char* gb0 = (const char*)(xh + (size_t)t0 * DD);
        const char* gb1 = (const char*)(xl + (size_t)t0 * DD);
        const char* gb2 = (const char*)(eh + (size_t)k0 * DD);
        const char* gb3 = (const char*)(el + (size_t)k0 * DD);
#pragma unroll
        for (int is = 0; is < 8; is++) {
            const int st = is >> 1;                        // compile-time per unroll
            int p = (is & 1) * 8192 + tid * 16;            // within-subtile byte pos
            int row = p >> 6;
            int slot = (p >> 4) & 3;
            int kgd = slot ^ ((row >> 1) & 3);             // pre-swizzle source
            const char* gb = (st == 0) ? gb0 : (st == 1) ? gb1 : (st == 2) ? gb2 : gb3;
            gaddr[is] = gb + (size_t)row * (DD * 2) + kgd * 16;
            laddr[is] = st * 16384 + p;
        }
    }

    f32x4 acc[8][4];
#pragma unroll
    for (int m = 0; m < 8; m++)
#pragma unroll
        for (int n = 0; n < 4; n++) {
            f32x4 z = {0.0f, 0.0f, 0.0f, 0.0f};
            acc[m][n] = z;
        }

    // prologue: stage K-step 0 into buf 0
#pragma unroll
    for (int is = 0; is < 8; is++)
        __builtin_amdgcn_global_load_lds(
            (const __attribute__((address_space(1))) unsigned int*)(gaddr[is]),
            (__attribute__((address_space(3))) unsigned int*)(lds + laddr[is]), 16, 0, 0);
    __syncthreads();

    int buf = 0;
    for (int t = 0; t < NT; t++) {
        // issue next K-step's stages first (overlap with this step's compute)
        if (t < NT - 1) {
            const int dcb = (t + 1) * (BK * 2);            // byte offset along rows
            char* lb = lds + (buf ^ 1) * 65536;
#pragma unroll
            for (int is = 0; is < 8; is++)
                __builtin_amdgcn_global_load_lds(
                    (const __attribute__((address_space(1))) unsigned int*)(gaddr[is] + dcb),
                    (__attribute__((address_space(3))) unsigned int*)(lb + laddr[is]), 16, 0, 0);
        }
        const char* cb = lds + buf * 65536;

        f16x8 fxh[8], feh[4], fel[4], fxl[8];
#pragma unroll
        for (int m = 0; m < 8; m++) {
            int row = wr * 128 + m * 16 + lrow;
            fxh[m] = *(const f16x8*)(cb + row * 64 + kgx);
        }
#pragma unroll
        for (int n = 0; n < 4; n++) {
            int row = wc * 64 + n * 16 + lrow;
            feh[n] = *(const f16x8*)(cb + 32768 + row * 64 + kgx);
        }
        __builtin_amdgcn_s_setprio(1);
#pragma unroll
        for (int m = 0; m < 8; m++)
#pragma unroll
            for (int n = 0; n < 4; n++)
                acc[m][n] = __builtin_amdgcn_mfma_f32_16x16x32_f16(fxh[m], feh[n], acc[m][n], 0, 0, 0);
        __builtin_amdgcn_s_setprio(0);

#pragma unroll
        for (int n = 0; n < 4; n++) {
            int row = wc * 64 + n * 16 + lrow;
            fel[n] = *(const f16x8*)(cb + 49152 + row * 64 + kgx);
        }
        __builtin_amdgcn_s_setprio(1);
#pragma unroll
        for (int m = 0; m < 8; m++)
#pragma unroll
            for (int n = 0; n < 4; n++)
                acc[m][n] = __builtin_amdgcn_mfma_f32_16x16x32_f16(fxh[m], fel[n], acc[m][n], 0, 0, 0);
        __builtin_amdgcn_s_setprio(0);

#pragma unroll
        for (int m = 0; m < 8; m++) {
            int row = wr * 128 + m * 16 + lrow;
            fxl[m] = *(const f16x8*)(cb + 16384 + row * 64 + kgx);
        }
        __builtin_amdgcn_s_setprio(1);
#pragma unroll
        for (int m = 0; m < 8; m++)
#pragma unroll
            for (int n = 0; n < 4; n++)
                acc[m][n] = __builtin_amdgcn_mfma_f32_16x16x32_f16(fxl[m], feh[n], acc[m][n], 0, 0, 0);
        __builtin_amdgcn_s_setprio(0);

        __syncthreads();     // compiler emits vmcnt(0) lgkmcnt(0) drain + s_barrier
        buf ^= 1;
    }

    // ---------------- epilogue: distances + argmin ----------------
    // C/D layout: col = lane&15, row = (lane>>4)*4 + reg (m89-verified)
    u64* red = (u64*)lds;                  // overlay on buffers (all reads done)
    if (tid < BM) red[tid] = 0xFFFFFFFFFFFFFFFFULL;
    __syncthreads();

    float se2[4];
#pragma unroll
    for (int n = 0; n < 4; n++) se2[n] = e2[k0 + wc * 64 + n * 16 + lrow];

#pragma unroll
    for (int m = 0; m < 8; m++) {
#pragma unroll
        for (int r = 0; r < 4; r++) {
            int rowl = wr * 128 + m * 16 + kg * 4 + r;
            float sx2 = x2[t0 + rowl];
            u64 b = 0xFFFFFFFFFFFFFFFFULL;
#pragma unroll
            for (int n = 0; n < 4; n++) {
                int kgl = k0 + wc * 64 + n * 16 + lrow;
                float s = sx2 + se2[n];           // rounded add (matches ref)
                float td = acc[m][n][r] * DESCALE; // exact pow2 scale
                asm volatile("" : "+v"(td));
                float dist = s - td;              // rounded sub (matches ref)
                u64 pk = ((u64)__float_as_uint(dist) << 32) | (unsigned)kgl;
                b = pk < b ? pk : b;
            }
#pragma unroll
            for (int off2 = 1; off2 < 16; off2 <<= 1) {
                u64 o = __shfl_xor(b, off2, 64);
                b = o < b ? o : b;
            }
            if (lrow == 0) atomicMin(&red[rowl], b);
        }
    }
    __syncthreads();
    if (tid < BM) atomicMin(&best[t0 + tid], red[tid]);
}

// ---------------- extract indices + counts ----------------
__global__ void vq_indices_kernel(const u64* __restrict__ best, int* __restrict__ indices,
                                  int* __restrict__ counts) {
    int t = blockIdx.x * 256 + threadIdx.x;
    int idx = (int)(best[t] & 0xFFFFFFFFULL);
    indices[t] = idx;
    atomicAdd(&counts[idx], 1);
}

// ---------------- new_N + N_sum ----------------
__global__ void vq_newN_kernel(const float* __restrict__ N, const int* __restrict__ counts,
                               float* __restrict__ outN, float* __restrict__ nsum) {
    int k = blockIdx.x * 256 + threadIdx.x;
    float a = 0.99f * N[k];
    float b = 0.01f * (float)counts[k];
    float nN = a + b;
    outN[k] = nN;
    float s = nN;
#pragma unroll
    for (int off = 32; off > 0; off >>= 1) s += __shfl_down(s, off, 64);
    __shared__ float wsum[4];
    int lane = threadIdx.x & 63, w = threadIdx.x >> 6;
    if (lane == 0) wsum[w] = s;
    __syncthreads();
    if (threadIdx.x == 0) atomicAdd(nsum, wsum[0] + wsum[1] + wsum[2] + wsum[3]);
}

// ---------------- fused: quantized_st write + sums scatter ----------------
__global__ void vq_gs_kernel(const float* __restrict__ x, const float* __restrict__ embT,
                             const int* __restrict__ indices, float* __restrict__ out0,
                             float* __restrict__ sums) {
    int t = blockIdx.x * 4 + (threadIdx.x >> 6);     // 4096 blocks, wave per token
    int lane = threadIdx.x & 63;
    int idx = indices[t];
    size_t o = (size_t)t * DD + lane * 4;
    float4 xv = *(const float4*)(x + o);
    float4 qv = *(const float4*)(embT + (size_t)idx * DD + lane * 4);
    float4 ov;
    ov.x = xv.x + (qv.x - xv.x);
    ov.y = xv.y + (qv.y - xv.y);
    ov.z = xv.z + (qv.z - xv.z);
    ov.w = xv.w + (qv.w - xv.w);
    *(float4*)(out0 + o) = ov;
    float* base = sums + (size_t)idx * DD + lane * 4;
    atomicAdd(base + 0, xv.x);
    atomicAdd(base + 1, xv.y);
    atomicAdd(base + 2, xv.z);
    atomicAdd(base + 3, xv.w);
}

// ---------------- new_m and new_embeddings ----------------
__global__ void vq_final_kernel(const float* __restrict__ m, const float* __restrict__ sums,
                                const float* __restrict__ outN, const float* __restrict__ nsum,
                                float* __restrict__ outEmb, float* __restrict__ outM) {
    int gid = blockIdx.x * 256 + threadIdx.x;
    int k = gid & (KK - 1);
    int d = gid >> 13;
    float Nsum = *nsum;
    float nN = outN[k];
    float scaled = (nN + 1e-5f) / (Nsum + 0.08192f) * Nsum;
    float a = 0.99f * m[gid];
    float b = 0.01f * sums[(size_t)k * DD + d];
    float mv = a + b;
    outM[gid] = mv;
    outEmb[gid] = mv / scaled;
}

extern "C" void kernel_launch(void* const* d_in, const int* in_sizes, int n_in,
                              void* d_out, int out_size, void* d_ws, size_t ws_size,
                              hipStream_t stream) {
    const float* x   = (const float*)d_in[0];   // [16384][256]
    const float* emb = (const float*)d_in[1];   // [256][8192]
    const float* Nin = (const float*)d_in[2];   // [8192]
    const float* min = (const float*)d_in[3];   // [256][8192]

    float* out0   = (float*)d_out;              // quantized_st  [4194304]
    float* outEmb = out0 + 4194304;             // new_embeddings [2097152]
    float* outN   = outEmb + 2097152;           // new_N [8192]
    float* outM   = outN + 8192;                // new_m [2097152]

    // workspace (floats)
    float* ws      = (float*)d_ws;
    float* sums    = ws;                        // 2097152
    float* e2buf   = ws + 2097152;              // 8192
    float* x2buf   = e2buf + 8192;              // 16384
    u64*   best    = (u64*)(x2buf + 16384);     // 16384 u64
    int*   idxbuf  = (int*)(best + 16384);      // 16384
    int*   counts  = idxbuf + 16384;            // 8192
    float* nsum    = (float*)(counts + 8192);   // 1

    // fp16 limbs + fp32 embT staged in output regions written later:
    f16* xhb = (f16*)out0;                      // 8 MB
    f16* xlb = xhb + 4194304;                   // 8 MB (out0 is 16 MB)
    f16* ehb = (f16*)outEmb;                    // 4 MB
    f16* elb = ehb + 2097152;                   // 4 MB (outEmb is 8 MB)
    float* embT = outM;                         // 8 MB, overwritten by vq_final last

    vq_init_kernel<<<2048, 256, 0, stream>>>(sums, best, counts, nsum);
    vq_e2_kernel<<<32, 256, 0, stream>>>(emb, e2buf);
    vq_x2split_kernel<<<4096, 256, 0, stream>>>(x, x2buf, xhb, xlb);
    vq_trsplit_kernel<<<dim3(256, 8), 256, 0, stream>>>(emb, embT, ehb, elb);
    vq_argmin_kernel<<<dim3(KK / BN, TOK / BM), 512, 131072, stream>>>(
        xhb, xlb, ehb, elb, x2buf, e2buf, best);
    vq_indices_kernel<<<64, 256, 0, stream>>>(best, idxbuf, counts);
    vq_newN_kernel<<<32, 256, 0, stream>>>(Nin, counts, outN, nsum);
    vq_gs_kernel<<<4096, 256, 0, stream>>>(x, embT, idxbuf, out0, sums);
    vq_final_kernel<<<8192, 256, 0, stream>>>(min, sums, outN, nsum, outEmb, outM);
}